// Round 4
// baseline (254.717 us; speedup 1.0000x reference)
//
#include <hip/hip_runtime.h>
#include <stdint.h>
#include <math.h>

#define NROW 32768
#define MCOL 2048
#define KDIM 128
#define NHEAD 8
#define SCALE 0.08838834764831845f  /* 1/sqrt(128) */

typedef __attribute__((ext_vector_type(8))) short short8;
typedef __attribute__((ext_vector_type(4))) float f32x4;

// ---------------- JAX threefry2x32, key = (0, 42) ----------------
__device__ __forceinline__ void tf2x32(uint32_t x0, uint32_t x1,
                                       uint32_t& o0, uint32_t& o1) {
  const uint32_t K0 = 0u, K1 = 42u, K2 = 0x1BD11BDAu ^ 0u ^ 42u;
  x0 += K0; x1 += K1;
#define TFROUND(r) { x0 += x1; x1 = (x1 << (r)) | (x1 >> (32 - (r))); x1 ^= x0; }
  TFROUND(13) TFROUND(15) TFROUND(26) TFROUND(6)
  x0 += K1; x1 += K2 + 1u;
  TFROUND(17) TFROUND(29) TFROUND(16) TFROUND(24)
  x0 += K2; x1 += K0 + 2u;
  TFROUND(13) TFROUND(15) TFROUND(26) TFROUND(6)
  x0 += K0; x1 += K1 + 3u;
  TFROUND(17) TFROUND(29) TFROUND(16) TFROUND(24)
  x0 += K1; x1 += K2 + 4u;
  TFROUND(13) TFROUND(15) TFROUND(26) TFROUND(6)
  x0 += K2; x1 += K0 + 5u;
#undef TFROUND
  o0 = x0; o1 = x1;
}

// JAX uniform(minval=tiny, maxval=1) bit path
__device__ __forceinline__ float bits_to_u(uint32_t b) {
  uint32_t fb = (b >> 9) | 0x3F800000u;
  float f = __uint_as_float(fb) - 1.0f;
  return (f == 0.0f) ? 1.17549435e-38f : f;
}

// ---------------- precompute: Wsum[d][e] = sum_h Wq[h*128+d][e]; bsum = 2*sum_h bq ----------------
__global__ void k_wsum(const float* __restrict__ Wq, const float* __restrict__ bq,
                       float* __restrict__ Wsum, float* __restrict__ bsum) {
  int t = blockIdx.x * 256 + threadIdx.x;
  if (t < KDIM * KDIM) {
    int d = t >> 7, e = t & 127;
    float s = 0.f;
#pragma unroll
    for (int h = 0; h < NHEAD; ++h) s += Wq[(h * KDIM + d) * KDIM + e];
    Wsum[t] = s;
  }
  if (blockIdx.x == 0 && threadIdx.x < KDIM) {
    int d = threadIdx.x;
    float s = 0.f;
#pragma unroll
    for (int h = 0; h < NHEAD; ++h) s += bq[h * KDIM + d];
    bsum[d] = 2.0f * s;
  }
}

// ---------------- precompute: cw_s[m][e] = SCALE * sum_d c[m][d]*Wsum[d][e];
//                  cb_s[m] = SCALE * sum_d bsum[d]*c[m][d];
//                  cwB = bf16 MFMA B-fragment layout of cw_s ----------------
__global__ void k_cw(const float* __restrict__ c, const float* __restrict__ Wsum,
                     const float* __restrict__ bsum,
                     float* __restrict__ cw_s, unsigned short* __restrict__ cwB16,
                     float* __restrict__ cb_s) {
  int m = blockIdx.x;
  int e = threadIdx.x;  // 128 threads
  __shared__ float crow[KDIM];
  if (e < 32) ((float4*)crow)[e] = ((const float4*)(c + (size_t)m * KDIM))[e];
  __syncthreads();
  float s = 0.f;
#pragma unroll 4
  for (int d = 0; d < KDIM; ++d) s += crow[d] * Wsum[d * KDIM + e];
  float sv = s * SCALE;
  cw_s[(size_t)m * KDIM + e] = sv;
  // B-frag: tile t = m>>4, col = m&15; k = e: ks = e>>5, grp = (e>>3)&3, j = e&7
  // lane = grp*16 + col;  ushort index = (((t*4+ks)*64 + lane)*8 + j)
  {
    int t = m >> 4, col = m & 15, ks = e >> 5, grp = (e >> 3) & 3, j = e & 7;
    int lane = grp * 16 + col;
    cwB16[(((size_t)(t * 4 + ks)) * 64 + lane) * 8 + j] =
        (unsigned short)(__float_as_uint(sv) >> 16);
  }
  if (e == 0) {
    float sb = 0.f;
    for (int d = 0; d < KDIM; ++d) sb += bsum[d] * crow[d];
    cb_s[m] = sb * SCALE;
  }
}

// ---------------- k_stats: bf16 MFMA logits GEMM -> per-row (mx, D'=sum exp(l)) ----------------
// 512 blocks x 256 threads (4 waves). Block: rows [R, R+64); wave w: rows R+16w..+15.
__launch_bounds__(256, 2)
__global__ void k_stats(const float* __restrict__ x1, const float* __restrict__ kin,
                        const uint4* __restrict__ cwB, const float* __restrict__ cb_s,
                        float* __restrict__ rowMx, float* __restrict__ rowD) {
  __shared__ uint4 Blds[4096];  // 64KB: 16 m-tiles * 4 ks * 64 lanes

  const int tid = threadIdx.x;
  const int w = tid >> 6, l = tid & 63;
  const int R = blockIdx.x * 64 + w * 16;
  const int rowA = R + (l & 15);
  const int kbase = (l >> 4) * 8;

  // A-fragments: lane l supplies A[row=l&15][k = ks*32 + (l>>4)*8 + j], j=0..7
  union { uint32_t u[4]; short8 s; } af[4];
#pragma unroll
  for (int ks = 0; ks < 4; ++ks) {
    const float* xp = x1 + (size_t)rowA * KDIM + ks * 32 + kbase;
    const float* kp = kin + (size_t)rowA * KDIM + ks * 32 + kbase;
    float4 a0 = *(const float4*)xp, a1 = *(const float4*)(xp + 4);
    float4 b0 = *(const float4*)kp, b1 = *(const float4*)(kp + 4);
    float f[8] = {a0.x + b0.x, a0.y + b0.y, a0.z + b0.z, a0.w + b0.w,
                  a1.x + b1.x, a1.y + b1.y, a1.z + b1.z, a1.w + b1.w};
#pragma unroll
    for (int r = 0; r < 4; ++r)
      af[ks].u[r] = (__float_as_uint(f[2 * r]) >> 16) |
                    (__float_as_uint(f[2 * r + 1]) & 0xFFFF0000u);
  }

  float mxs[4], Ds[4];
#pragma unroll
  for (int r = 0; r < 4; ++r) { mxs[r] = -INFINITY; Ds[r] = 0.f; }

  for (int ch = 0; ch < 8; ++ch) {
    __syncthreads();
    // stage 16 m-tiles of B-frags (64KB), coalesced
    const uint4* src = cwB + (size_t)ch * 4096;
#pragma unroll
    for (int r = 0; r < 16; ++r) Blds[r * 256 + tid] = src[r * 256 + tid];
    __syncthreads();

#pragma unroll 2
    for (int t = 0; t < 16; ++t) {
      f32x4 acc = {0.f, 0.f, 0.f, 0.f};
#pragma unroll
      for (int ks = 0; ks < 4; ++ks) {
        union { uint4 v; short8 s; } bf;
        bf.v = Blds[(t * 4 + ks) * 64 + l];
        acc = __builtin_amdgcn_mfma_f32_16x16x32_bf16(af[ks].s, bf.s, acc, 0, 0, 0);
      }
      int m = ch * 256 + t * 16 + (l & 15);
      float cbv = cb_s[m];
#pragma unroll
      for (int r = 0; r < 4; ++r) {
        float lv = acc[r] + cbv;   // logit[n = R + (l>>4)*4 + r][m]
        mxs[r] = fmaxf(mxs[r], lv);
        Ds[r] += __expf(lv);
      }
    }
  }

  // reduce over the 16 lanes (l&15) that share the same 4 rows
#pragma unroll
  for (int s = 1; s < 16; s <<= 1) {
#pragma unroll
    for (int r = 0; r < 4; ++r) {
      mxs[r] = fmaxf(mxs[r], __shfl_xor(mxs[r], s));
      Ds[r] += __shfl_xor(Ds[r], s);
    }
  }
  if ((l & 15) == 0) {
#pragma unroll
    for (int r = 0; r < 4; ++r) {
      int n = R + (l >> 4) * 4 + r;
      rowMx[n] = mxs[r];
      rowD[n] = Ds[r];
    }
  }
}

// ---------------- k_prng: threefry scan + top-2 + fixup + fused scatter ----------------
// 1024 blocks x 256 threads; wave per row-group, 8 rows per wave.
__launch_bounds__(256, 4)
__global__ void k_prng(const float* __restrict__ x1, const float* __restrict__ kin,
                       const float* __restrict__ cw_s, const float* __restrict__ cb_s,
                       const float* __restrict__ rowMx, const float* __restrict__ rowD,
                       float* __restrict__ accum) {
  const int lane = threadIdx.x & 63;
  const int wgid = blockIdx.x * 4 + (threadIdx.x >> 6);

  for (int rr = 0; rr < 8; ++rr) {
    const int n = wgid * 8 + rr;
    const uint32_t base = (uint32_t)n * (uint32_t)MCOL;

    uint32_t t0 = 0u, t1 = 0u;
    int m0 = 0, m1 = 0;
#pragma unroll 4
    for (int jj = 0; jj < 32; ++jj) {
      uint32_t mm = (uint32_t)lane + 64u * (uint32_t)jj;
      uint32_t o0, o1;
      tf2x32(0u, base + mm, o0, o1);
      uint32_t b = o0 ^ o1;
      bool gt0 = b > t0;
      bool gt1 = b > t1;
      t1 = gt0 ? t0 : (gt1 ? b : t1);
      m1 = gt0 ? m0 : (gt1 ? (int)mm : m1);
      t0 = gt0 ? b : t0;
      m0 = gt0 ? (int)mm : m0;
    }

    float u0 = bits_to_u(t0), u1 = bits_to_u(t1);
    float g0 = -logf(-logf(u0));
    float g1 = -logf(-logf(u1));
    float gmax = g0;
#pragma unroll
    for (int s = 1; s < 64; s <<= 1) gmax = fmaxf(gmax, __shfl_xor(gmax, s));

    const float mx = rowMx[n], Dp = rowD[n];
    // pmax bound inflated for bf16-stat error (common-mode cancels in p_a vs p_b)
    const float thresh = gmax - (__expf(mx) * 1.05f / Dp + 2e-4f);

    // row data (coalesced: 8B/lane)
    const float2 xa = ((const float2*)(x1 + (size_t)n * KDIM))[lane];
    const float2 xb = ((const float2*)(kin + (size_t)n * KDIM))[lane];
    const float xk0 = xa.x + xb.x, xk1 = xa.y + xb.y;

    float bestSc = -INFINITY;
    int bestM = 0x7FFFFFFF;
#pragma unroll
    for (int ph = 0; ph < 2; ++ph) {
      float g = ph ? g1 : g0;
      int mI = ph ? m1 : m0;
      unsigned long long bl = __ballot(g >= thresh);
      while (bl) {
        int src = __ffsll(bl) - 1;
        bl &= bl - 1ull;
        int m = __shfl(mI, src);
        float gc = __shfl(g, src);
        const float2 cv = ((const float2*)(cw_s + (size_t)m * KDIM))[lane];
        float part = xk0 * cv.x + xk1 * cv.y;
#pragma unroll
        for (int s = 1; s < 64; s <<= 1) part += __shfl_xor(part, s);
        float lv = part + cb_s[m];
        float p = __expf(lv) / Dp;   // = exp(l - mx)/D, since D = D' * exp(-mx)
        float sc = p + gc;
        if (sc > bestSc || (sc == bestSc && m < bestM)) { bestSc = sc; bestM = m; }
      }
    }

    // fused scatter: accum[bestM] += x1[n]
    float* dst = accum + (size_t)bestM * KDIM + lane * 2;
    atomicAdd(dst + 0, xa.x);
    atomicAdd(dst + 1, xa.y);
  }
}

// ---------------- final: out = accum @ Wd.T + bd ----------------
__global__ void k_final(const float* __restrict__ acc, const float* __restrict__ Wd,
                        const float* __restrict__ bd, float* __restrict__ out) {
  int m = blockIdx.x, j = threadIdx.x;  // 128 threads
  __shared__ float ar[KDIM];
  if (j < 32) ((float4*)ar)[j] = ((const float4*)(acc + (size_t)m * KDIM))[j];
  __syncthreads();
  const float4* wr = (const float4*)(Wd + (size_t)j * KDIM);
  float s = 0.f;
#pragma unroll
  for (int e4 = 0; e4 < 32; ++e4) {
    float4 wv = wr[e4];
    s += wv.x * ar[4 * e4 + 0] + wv.y * ar[4 * e4 + 1]
       + wv.z * ar[4 * e4 + 2] + wv.w * ar[4 * e4 + 3];
  }
  out[(size_t)m * KDIM + j] = s + bd[j];
}

extern "C" void kernel_launch(void* const* d_in, const int* in_sizes, int n_in,
                              void* d_out, int out_size, void* d_ws, size_t ws_size,
                              hipStream_t stream) {
  const float* x1 = (const float*)d_in[0];
  const float* k  = (const float*)d_in[1];
  const float* c  = (const float*)d_in[2];
  const float* Wq = (const float*)d_in[3];
  const float* bq = (const float*)d_in[4];
  const float* Wd = (const float*)d_in[5];
  const float* bd = (const float*)d_in[6];
  float* out = (float*)d_out;

  char* ws = (char*)d_ws;
  size_t off = 0;
  float* cw_s = (float*)(ws + off); off += (size_t)MCOL * KDIM * 4;          // 1MB
  float* cb_s = (float*)(ws + off); off += 8192;                             // 8KB
  unsigned short* cwB = (unsigned short*)(ws + off); off += (size_t)MCOL * KDIM * 2; // 512KB
  float* Wsum = (float*)(ws + off); off += KDIM * KDIM * 4;                  // 64KB
  float* bsum = (float*)(ws + off); off += 512;
  float* rowMx = (float*)(ws + off); off += (size_t)NROW * 4;                // 128KB
  float* rowD  = (float*)(ws + off); off += (size_t)NROW * 4;                // 128KB
  float* accum = (float*)(ws + off); off += (size_t)MCOL * KDIM * 4;         // 1MB

  hipMemsetAsync(accum, 0, (size_t)MCOL * KDIM * sizeof(float), stream);
  k_wsum<<<64, 256, 0, stream>>>(Wq, bq, Wsum, bsum);
  k_cw<<<MCOL, 128, 0, stream>>>(c, Wsum, bsum, cw_s, cwB, cb_s);
  k_stats<<<512, 256, 0, stream>>>(x1, k, (const uint4*)cwB, cb_s, rowMx, rowD);
  k_prng<<<1024, 256, 0, stream>>>(x1, k, cw_s, cb_s, rowMx, rowD, accum);
  k_final<<<MCOL, 128, 0, stream>>>(accum, Wd, bd, out);
}

// Round 5
// 212.827 us; speedup vs baseline: 1.1968x; 1.1968x over previous
//
#include <hip/hip_runtime.h>
#include <stdint.h>
#include <math.h>

#define NROW 32768
#define MCOL 2048
#define KDIM 128
#define NHEAD 8
#define SCALE 0.08838834764831845f  /* 1/sqrt(128) */
#define STATS_BLOCKS 512
#define SCAN_BLOCKS 1024
#define CAND_MAX 32

typedef __attribute__((ext_vector_type(8))) short short8;
typedef __attribute__((ext_vector_type(4))) float f32x4;

__device__ __forceinline__ uint32_t rotl32(uint32_t x, uint32_t r) {
  return __builtin_amdgcn_alignbit(x, x, 32u - r);
}
__device__ __forceinline__ uint32_t umin3(uint32_t a, uint32_t b, uint32_t c) {
  return min(min(a, b), c);
}

// threefry2x32 with key=(0,42), input (0, c); returns o0 ^ o1 (JAX partitionable 32-bit draw)
__device__ __forceinline__ uint32_t tf_hash(uint32_t c) {
  const uint32_t K2 = 0x1BD11BDAu ^ 0u ^ 42u;
  uint32_t x0 = 0u, x1 = c + 42u;
#define R4A { x0 += x1; x1 = rotl32(x1,13); x1 ^= x0; \
              x0 += x1; x1 = rotl32(x1,15); x1 ^= x0; \
              x0 += x1; x1 = rotl32(x1,26); x1 ^= x0; \
              x0 += x1; x1 = rotl32(x1, 6); x1 ^= x0; }
#define R4B { x0 += x1; x1 = rotl32(x1,17); x1 ^= x0; \
              x0 += x1; x1 = rotl32(x1,29); x1 ^= x0; \
              x0 += x1; x1 = rotl32(x1,16); x1 ^= x0; \
              x0 += x1; x1 = rotl32(x1,24); x1 ^= x0; }
  R4A x0 += 42u;      x1 += K2 + 1u;
  R4B x0 += K2;       x1 += 2u;
  R4A /* x0 += 0 */   x1 += 42u + 3u;
  R4B x0 += 42u;      x1 += K2 + 4u;
  R4A x0 += K2;       x1 += 5u;
#undef R4A
#undef R4B
  return x0 ^ x1;
}

// JAX uniform(minval=tiny, maxval=1) bit path (low 9 bits of b ignored)
__device__ __forceinline__ float bits_to_u(uint32_t b) {
  uint32_t fb = (b >> 9) | 0x3F800000u;
  float f = __uint_as_float(fb) - 1.0f;
  return (f == 0.0f) ? 1.17549435e-38f : f;
}

// ---------------- precompute: Wsum[d][e] = sum_h Wq[h*128+d][e]; bsum = 2*sum_h bq ----------------
__global__ void k_wsum(const float* __restrict__ Wq, const float* __restrict__ bq,
                       float* __restrict__ Wsum, float* __restrict__ bsum) {
  int t = blockIdx.x * 256 + threadIdx.x;
  if (t < KDIM * KDIM) {
    int d = t >> 7, e = t & 127;
    float s = 0.f;
#pragma unroll
    for (int h = 0; h < NHEAD; ++h) s += Wq[(h * KDIM + d) * KDIM + e];
    Wsum[t] = s;
  }
  if (blockIdx.x == 0 && threadIdx.x < KDIM) {
    int d = threadIdx.x;
    float s = 0.f;
#pragma unroll
    for (int h = 0; h < NHEAD; ++h) s += bq[h * KDIM + d];
    bsum[d] = 2.0f * s;
  }
}

// ---------------- precompute: cw_s, cb_s, cwB (bf16 MFMA B-fragments) ----------------
__global__ void k_cw(const float* __restrict__ c, const float* __restrict__ Wsum,
                     const float* __restrict__ bsum,
                     float* __restrict__ cw_s, unsigned short* __restrict__ cwB16,
                     float* __restrict__ cb_s) {
  int m = blockIdx.x;
  int e = threadIdx.x;  // 128 threads
  __shared__ float crow[KDIM];
  if (e < 32) ((float4*)crow)[e] = ((const float4*)(c + (size_t)m * KDIM))[e];
  __syncthreads();
  float s = 0.f;
#pragma unroll 4
  for (int d = 0; d < KDIM; ++d) s += crow[d] * Wsum[d * KDIM + e];
  float sv = s * SCALE;
  cw_s[(size_t)m * KDIM + e] = sv;
  {
    int t = m >> 4, col = m & 15, ks = e >> 5, grp = (e >> 3) & 3, j = e & 7;
    int lane = grp * 16 + col;
    cwB16[(((size_t)(t * 4 + ks)) * 64 + lane) * 8 + j] =
        (unsigned short)(__float_as_uint(sv) >> 16);
  }
  if (e == 0) {
    float sb = 0.f;
    for (int d = 0; d < KDIM; ++d) sb += bsum[d] * crow[d];
    cb_s[m] = sb * SCALE;
  }
}

// ---------------- fused: stats role (MFMA) + scan role (threefry) ----------------
// blocks [0, STATS_BLOCKS): bf16 MFMA logits -> rowMx, rowD (no LDS; cwB from L2)
// blocks [STATS_BLOCKS, +SCAN_BLOCKS): PRNG scan -> conservative candidate lists
__launch_bounds__(256, 4)
__global__ void k_fused(const float* __restrict__ x1, const float* __restrict__ kin,
                        const uint4* __restrict__ cwB, const float* __restrict__ cb_s,
                        float* __restrict__ rowMx, float* __restrict__ rowD,
                        uint2* __restrict__ cand, int* __restrict__ cnts) {
  const int tid = threadIdx.x;
  const int wv = tid >> 6, lane = tid & 63;

  if (blockIdx.x < STATS_BLOCKS) {
    // ================= stats role =================
    const int R = blockIdx.x * 64 + wv * 16;
    const int rowA = R + (lane & 15);
    const int kbase = (lane >> 4) * 8;

    union { uint32_t u[4]; short8 s; } af[4];
#pragma unroll
    for (int ks = 0; ks < 4; ++ks) {
      const float* xp = x1 + (size_t)rowA * KDIM + ks * 32 + kbase;
      const float* kp = kin + (size_t)rowA * KDIM + ks * 32 + kbase;
      float4 a0 = *(const float4*)xp, a1 = *(const float4*)(xp + 4);
      float4 b0 = *(const float4*)kp, b1 = *(const float4*)(kp + 4);
      float f[8] = {a0.x + b0.x, a0.y + b0.y, a0.z + b0.z, a0.w + b0.w,
                    a1.x + b1.x, a1.y + b1.y, a1.z + b1.z, a1.w + b1.w};
#pragma unroll
      for (int r = 0; r < 4; ++r)
        af[ks].u[r] = (__float_as_uint(f[2 * r]) >> 16) |
                      (__float_as_uint(f[2 * r + 1]) & 0xFFFF0000u);
    }

    float mxs[4], Ds[4];
#pragma unroll
    for (int r = 0; r < 4; ++r) { mxs[r] = -INFINITY; Ds[r] = 0.f; }

#pragma unroll 2
    for (int t = 0; t < 128; ++t) {
      f32x4 acc = {0.f, 0.f, 0.f, 0.f};
#pragma unroll
      for (int ks = 0; ks < 4; ++ks) {
        union { uint4 v; short8 s; } bf;
        bf.v = cwB[(size_t)(t * 4 + ks) * 64 + lane];
        acc = __builtin_amdgcn_mfma_f32_16x16x32_bf16(af[ks].s, bf.s, acc, 0, 0, 0);
      }
      float cbv = cb_s[t * 16 + (lane & 15)];
#pragma unroll
      for (int r = 0; r < 4; ++r) {
        float lv = acc[r] + cbv;
        mxs[r] = fmaxf(mxs[r], lv);
        Ds[r] += __expf(lv);
      }
    }

#pragma unroll
    for (int s = 1; s < 16; s <<= 1) {
#pragma unroll
      for (int r = 0; r < 4; ++r) {
        mxs[r] = fmaxf(mxs[r], __shfl_xor(mxs[r], s));
        Ds[r] += __shfl_xor(Ds[r], s);
      }
    }
    if ((lane & 15) == 0) {
#pragma unroll
      for (int r = 0; r < 4; ++r) {
        int n = R + (lane >> 4) * 4 + r;
        rowMx[n] = mxs[r];
        rowD[n] = Ds[r];
      }
    }
  } else {
    // ================= scan role =================
    const int wgid = (blockIdx.x - STATS_BLOCKS) * 4 + wv;  // 0..4095
    for (int rr = 0; rr < 8; ++rr) {
      const int n = wgid * 8 + rr;
      const uint32_t c0 = (uint32_t)n * (uint32_t)MCOL + (uint32_t)lane;

      uint32_t t0 = 0u, t1 = 0u, t2 = 0u;
#pragma unroll 8
      for (uint32_t jj = 0; jj < 32; ++jj) {
        uint32_t b = tf_hash(c0 + 64u * jj);
        uint32_t key = (b & 0xFFFFFE00u) | jj;     // u-bits | jj (m = lane | jj<<6)
        t2 = max(t2, umin3(t0, t1, key));
        t1 = max(t1, min(t0, key));
        t0 = max(t0, key);
      }

      // wave max key -> conservative u-space threshold: g >= g* - ln(1.30)
      uint32_t kmax = t0;
#pragma unroll
      for (int s = 1; s < 64; s <<= 1)
        kmax = max(kmax, (uint32_t)__shfl_xor((int)kmax, s));
      float ustar = bits_to_u(kmax);
      float uthr = __expf(1.30f * __logf(ustar));  // = ustar^1.30
      uint32_t bthr = (__float_as_uint(uthr + 1.0f) & 0x007FFFFFu) << 9;
      if (bthr >= 512u) bthr -= 512u;  // widen 1 u-ulp for float slop

      uint32_t base_idx = 0;
      uint2* crow = cand + (size_t)n * CAND_MAX;
#pragma unroll
      for (int s = 0; s < 3; ++s) {
        uint32_t tk = (s == 0) ? t0 : ((s == 1) ? t1 : t2);
        bool pred = tk >= bthr;
        unsigned long long mk = __ballot(pred);
        uint32_t pos = base_idx + (uint32_t)__popcll(mk & ((1ull << lane) - 1ull));
        if (pred && pos < CAND_MAX) {
          uint32_t m = (uint32_t)lane | ((tk & 31u) << 6);
          crow[pos] = make_uint2(tk & 0xFFFFFE00u, m);
        }
        base_idx += (uint32_t)__popcll(mk);
      }
      cnts[n] = (int)base_idx;
    }
  }
}

// ---------------- k_fix: exact adjudication + fused scatter ----------------
__launch_bounds__(256, 4)
__global__ void k_fix(const float* __restrict__ x1, const float* __restrict__ kin,
                      const float* __restrict__ cw_s, const float* __restrict__ cb_s,
                      const float* __restrict__ rowMx, const float* __restrict__ rowD,
                      const uint2* __restrict__ cand, const int* __restrict__ cnts,
                      float* __restrict__ accum) {
  __shared__ float xksh[4][KDIM];  // only used by the (near-dead) fallback path
  const int tid = threadIdx.x;
  const int wv = tid >> 6, lane = tid & 63;
  const int wgid = blockIdx.x * 4 + wv;  // 0..2047

  for (int rr = 0; rr < 16; ++rr) {
    const int n = wgid * 16 + rr;
    const int cnt = cnts[n];
    const float mx = rowMx[n], Dp = rowD[n];
    const float pmax = expf(mx) / Dp;

    const float2 xa = ((const float2*)(x1 + (size_t)n * KDIM))[lane];
    const float2 xb = ((const float2*)(kin + (size_t)n * KDIM))[lane];
    const float xk0 = xa.x + xb.x, xk1 = xa.y + xb.y;

    float bestSc = -INFINITY;
    int bestM = 0x7FFFFFFF;

    if (cnt > CAND_MAX || pmax > 0.2f) {
      // -------- exact full-rescan fallback (probability ~0, correctness valve) --------
      xksh[wv][lane * 2] = xk0;
      xksh[wv][lane * 2 + 1] = xk1;
      __builtin_amdgcn_s_waitcnt(0);  // drain lgkm for same-wave LDS RAW
      for (uint32_t jj = 0; jj < 32; ++jj) {
        uint32_t m = (uint32_t)lane | (jj << 6);
        uint32_t b = tf_hash((uint32_t)n * (uint32_t)MCOL + m);
        float u = bits_to_u(b);
        float g = -logf(-logf(u));
        float l = 0.f;
        for (int e = 0; e < KDIM; ++e) l += xksh[wv][e] * cw_s[(size_t)m * KDIM + e];
        float p = __expf(l + cb_s[m]) / Dp;
        float sc = p + g;
        if (sc > bestSc || (sc == bestSc && (int)m < bestM)) { bestSc = sc; bestM = (int)m; }
      }
#pragma unroll
      for (int s = 1; s < 64; s <<= 1) {
        float os = __shfl_xor(bestSc, s);
        int om = __shfl_xor(bestM, s);
        if (os > bestSc || (os == bestSc && om < bestM)) { bestSc = os; bestM = om; }
      }
    } else {
      // -------- normal path: adjudicate stored candidates --------
      uint2 cd = make_uint2(0u, 0u);
      float g = -INFINITY;
      if (lane < cnt) {
        cd = cand[(size_t)n * CAND_MAX + lane];
        g = -logf(-logf(bits_to_u(cd.x)));
      }
      float g1 = g;
#pragma unroll
      for (int s = 1; s < 64; s <<= 1) g1 = fmaxf(g1, __shfl_xor(g1, s));
      const float thr = g1 - (pmax * 1.05f + 2e-4f);

      unsigned long long bl = __ballot(lane < cnt && g >= thr);
      while (bl) {
        int src = __ffsll(bl) - 1;
        bl &= bl - 1ull;
        int m = __shfl((int)cd.y, src);
        float gc = __shfl(g, src);
        const float2 cv = ((const float2*)(cw_s + (size_t)m * KDIM))[lane];
        float part = xk0 * cv.x + xk1 * cv.y;
#pragma unroll
        for (int s = 1; s < 64; s <<= 1) part += __shfl_xor(part, s);
        float p = __expf(part + cb_s[m]) / Dp;
        float sc = p + gc;
        if (sc > bestSc || (sc == bestSc && m < bestM)) { bestSc = sc; bestM = m; }
      }
    }

    float* dst = accum + (size_t)bestM * KDIM + lane * 2;
    atomicAdd(dst + 0, xa.x);
    atomicAdd(dst + 1, xa.y);
  }
}

// ---------------- final: out = accum @ Wd.T + bd ----------------
__global__ void k_final(const float* __restrict__ acc, const float* __restrict__ Wd,
                        const float* __restrict__ bd, float* __restrict__ out) {
  int m = blockIdx.x, j = threadIdx.x;  // 128 threads
  __shared__ float ar[KDIM];
  if (j < 32) ((float4*)ar)[j] = ((const float4*)(acc + (size_t)m * KDIM))[j];
  __syncthreads();
  const float4* wr = (const float4*)(Wd + (size_t)j * KDIM);
  float s = 0.f;
#pragma unroll
  for (int e4 = 0; e4 < 32; ++e4) {
    float4 wv = wr[e4];
    s += wv.x * ar[4 * e4 + 0] + wv.y * ar[4 * e4 + 1]
       + wv.z * ar[4 * e4 + 2] + wv.w * ar[4 * e4 + 3];
  }
  out[(size_t)m * KDIM + j] = s + bd[j];
}

extern "C" void kernel_launch(void* const* d_in, const int* in_sizes, int n_in,
                              void* d_out, int out_size, void* d_ws, size_t ws_size,
                              hipStream_t stream) {
  const float* x1 = (const float*)d_in[0];
  const float* k  = (const float*)d_in[1];
  const float* c  = (const float*)d_in[2];
  const float* Wq = (const float*)d_in[3];
  const float* bq = (const float*)d_in[4];
  const float* Wd = (const float*)d_in[5];
  const float* bd = (const float*)d_in[6];
  float* out = (float*)d_out;

  char* ws = (char*)d_ws;
  size_t off = 0;
  float* cw_s = (float*)(ws + off); off += (size_t)MCOL * KDIM * 4;                   // 1MB
  float* cb_s = (float*)(ws + off); off += 8192;                                      // 8KB
  unsigned short* cwB = (unsigned short*)(ws + off); off += (size_t)MCOL * KDIM * 2;  // 512KB
  float* Wsum = (float*)(ws + off); off += KDIM * KDIM * 4;                           // 64KB
  float* bsum = (float*)(ws + off); off += 4096;
  float* rowMx = (float*)(ws + off); off += (size_t)NROW * 4;                         // 128KB
  float* rowD  = (float*)(ws + off); off += (size_t)NROW * 4;                         // 128KB
  float* accum = (float*)(ws + off); off += (size_t)MCOL * KDIM * 4;                  // 1MB
  int*   cnts  = (int*)(ws + off);  off += (size_t)NROW * 4;                          // 128KB
  uint2* cand  = (uint2*)(ws + off); off += (size_t)NROW * CAND_MAX * 8;              // 8MB

  hipMemsetAsync(accum, 0, (size_t)MCOL * KDIM * sizeof(float), stream);
  k_wsum<<<64, 256, 0, stream>>>(Wq, bq, Wsum, bsum);
  k_cw<<<MCOL, 128, 0, stream>>>(c, Wsum, bsum, cw_s, cwB, cb_s);
  k_fused<<<STATS_BLOCKS + SCAN_BLOCKS, 256, 0, stream>>>(x1, k, (const uint4*)cwB,
                                                          cb_s, rowMx, rowD, cand, cnts);
  k_fix<<<512, 256, 0, stream>>>(x1, k, cw_s, cb_s, rowMx, rowD, cand, cnts, accum);
  k_final<<<MCOL, 128, 0, stream>>>(accum, Wd, bd, out);
}

// Round 6
// 207.016 us; speedup vs baseline: 1.2304x; 1.0281x over previous
//
#include <hip/hip_runtime.h>
#include <stdint.h>
#include <math.h>

#define NROW 32768
#define MCOL 2048
#define KDIM 128
#define NHEAD 8
#define SCALE 0.08838834764831845f  /* 1/sqrt(128) */

typedef __attribute__((ext_vector_type(8))) short short8;
typedef __attribute__((ext_vector_type(4))) float f32x4;

__device__ __forceinline__ uint32_t rotl32(uint32_t x, uint32_t r) {
  return __builtin_amdgcn_alignbit(x, x, 32u - r);
}

// threefry2x32 with key=(0,42), input (0, c); returns o0 ^ o1 (JAX partitionable 32-bit draw)
__device__ __forceinline__ uint32_t tf_hash(uint32_t c) {
  const uint32_t K2 = 0x1BD11BDAu ^ 0u ^ 42u;
  uint32_t x0 = 0u, x1 = c + 42u;
#define R4A { x0 += x1; x1 = rotl32(x1,13); x1 ^= x0; \
              x0 += x1; x1 = rotl32(x1,15); x1 ^= x0; \
              x0 += x1; x1 = rotl32(x1,26); x1 ^= x0; \
              x0 += x1; x1 = rotl32(x1, 6); x1 ^= x0; }
#define R4B { x0 += x1; x1 = rotl32(x1,17); x1 ^= x0; \
              x0 += x1; x1 = rotl32(x1,29); x1 ^= x0; \
              x0 += x1; x1 = rotl32(x1,16); x1 ^= x0; \
              x0 += x1; x1 = rotl32(x1,24); x1 ^= x0; }
  R4A x0 += 42u;      x1 += K2 + 1u;
  R4B x0 += K2;       x1 += 2u;
  R4A /* x0 += 0 */   x1 += 42u + 3u;
  R4B x0 += 42u;      x1 += K2 + 4u;
  R4A x0 += K2;       x1 += 5u;
#undef R4A
#undef R4B
  return x0 ^ x1;
}

// JAX uniform(minval=tiny, maxval=1) bit path (low 9 bits of b ignored)
__device__ __forceinline__ float bits_to_u(uint32_t b) {
  uint32_t fb = (b >> 9) | 0x3F800000u;
  float f = __uint_as_float(fb) - 1.0f;
  return (f == 0.0f) ? 1.17549435e-38f : f;
}

__device__ __forceinline__ float gumbel_of_key(uint32_t key) {
  float u = bits_to_u(key);
  return -logf(-logf(u));
}

// ---------------- precompute: Wsum[d][e] = sum_h Wq[h*128+d][e]; bsum = 2*sum_h bq ----------------
__global__ void k_wsum(const float* __restrict__ Wq, const float* __restrict__ bq,
                       float* __restrict__ Wsum, float* __restrict__ bsum) {
  int t = blockIdx.x * 256 + threadIdx.x;
  if (t < KDIM * KDIM) {
    int d = t >> 7, e = t & 127;
    float s = 0.f;
#pragma unroll
    for (int h = 0; h < NHEAD; ++h) s += Wq[(h * KDIM + d) * KDIM + e];
    Wsum[t] = s;
  }
  if (blockIdx.x == 0 && threadIdx.x < KDIM) {
    int d = threadIdx.x;
    float s = 0.f;
#pragma unroll
    for (int h = 0; h < NHEAD; ++h) s += bq[h * KDIM + d];
    bsum[d] = 2.0f * s;
  }
}

// ---------------- precompute: cw_s, cb_s, cwB (bf16 MFMA B-fragments) ----------------
__global__ void k_cw(const float* __restrict__ c, const float* __restrict__ Wsum,
                     const float* __restrict__ bsum,
                     float* __restrict__ cw_s, unsigned short* __restrict__ cwB16,
                     float* __restrict__ cb_s) {
  int m = blockIdx.x;
  int e = threadIdx.x;  // 128 threads
  __shared__ float crow[KDIM];
  if (e < 32) ((float4*)crow)[e] = ((const float4*)(c + (size_t)m * KDIM))[e];
  __syncthreads();
  float s = 0.f;
#pragma unroll 4
  for (int d = 0; d < KDIM; ++d) s += crow[d] * Wsum[d * KDIM + e];
  float sv = s * SCALE;
  cw_s[(size_t)m * KDIM + e] = sv;
  {
    int t = m >> 4, col = m & 15, ks = e >> 5, grp = (e >> 3) & 3, j = e & 7;
    int lane = grp * 16 + col;
    cwB16[(((size_t)(t * 4 + ks)) * 64 + lane) * 8 + j] =
        (unsigned short)(__float_as_uint(sv) >> 16);
  }
  if (e == 0) {
    float sb = 0.f;
    for (int d = 0; d < KDIM; ++d) sb += bsum[d] * crow[d];
    cb_s[m] = sb * SCALE;
  }
}

// ---------------- k_mega: stats (waves 0-1) + scan (all) + adjudicate + scatter ----------------
// 1024 blocks x 256 threads. Block b owns rows [32b, 32b+32).
//   wv0: MFMA stats rows [B,B+16) -> LDS; then scan rows B+0..5
//   wv1: MFMA stats rows [B+16,B+32) -> LDS; then scan rows B+6..11
//   wv2: scan rows B+12..21;  wv3: scan rows B+22..31
// __syncthreads, then each wave adjudicates + scatters its scan rows.
__launch_bounds__(256, 4)
__global__ void k_mega(const float* __restrict__ x1, const float* __restrict__ kin,
                       const uint4* __restrict__ cwB, const float* __restrict__ cb_s,
                       const float* __restrict__ cw_s, float* __restrict__ accum) {
  __shared__ float smx[32];
  __shared__ float sD[32];
  __shared__ float xksh[4][KDIM];  // fallback-only scratch (2KB)

  const int tid = threadIdx.x;
  const int wv = tid >> 6, lane = tid & 63;
  const int B = blockIdx.x * 32;
  const int sstart = 6 * wv + ((wv >= 2) ? 4 * (wv - 2) : 0);  // 0,6,12,22
  const int scnt = (wv < 2) ? 6 : 10;

  // ================= stats role (waves 0,1) =================
  if (wv < 2) {
    const int R = B + wv * 16;
    const int rowA = R + (lane & 15);
    const int kbase = (lane >> 4) * 8;

    union { uint32_t u[4]; short8 s; } af[4];
#pragma unroll
    for (int ks = 0; ks < 4; ++ks) {
      const float* xp = x1 + (size_t)rowA * KDIM + ks * 32 + kbase;
      const float* kp = kin + (size_t)rowA * KDIM + ks * 32 + kbase;
      float4 a0 = *(const float4*)xp, a1 = *(const float4*)(xp + 4);
      float4 b0 = *(const float4*)kp, b1 = *(const float4*)(kp + 4);
      float f[8] = {a0.x + b0.x, a0.y + b0.y, a0.z + b0.z, a0.w + b0.w,
                    a1.x + b1.x, a1.y + b1.y, a1.z + b1.z, a1.w + b1.w};
#pragma unroll
      for (int r = 0; r < 4; ++r)
        af[ks].u[r] = (__float_as_uint(f[2 * r]) >> 16) |
                      (__float_as_uint(f[2 * r + 1]) & 0xFFFF0000u);
    }

    float mxs[4], Ds[4];
#pragma unroll
    for (int r = 0; r < 4; ++r) { mxs[r] = -INFINITY; Ds[r] = 0.f; }

#pragma unroll 2
    for (int t = 0; t < 128; ++t) {
      f32x4 acc = {0.f, 0.f, 0.f, 0.f};
#pragma unroll
      for (int ks = 0; ks < 4; ++ks) {
        union { uint4 v; short8 s; } bf;
        bf.v = cwB[(size_t)(t * 4 + ks) * 64 + lane];
        acc = __builtin_amdgcn_mfma_f32_16x16x32_bf16(af[ks].s, bf.s, acc, 0, 0, 0);
      }
      float cbv = cb_s[t * 16 + (lane & 15)];
#pragma unroll
      for (int r = 0; r < 4; ++r) {
        float lv = acc[r] + cbv;
        mxs[r] = fmaxf(mxs[r], lv);
        Ds[r] += __expf(lv);
      }
    }

#pragma unroll
    for (int s = 1; s < 16; s <<= 1) {
#pragma unroll
      for (int r = 0; r < 4; ++r) {
        mxs[r] = fmaxf(mxs[r], __shfl_xor(mxs[r], s));
        Ds[r] += __shfl_xor(Ds[r], s);
      }
    }
    if ((lane & 15) == 0) {
#pragma unroll
      for (int r = 0; r < 4; ++r) {
        int lr = wv * 16 + (lane >> 4) * 4 + r;
        smx[lr] = mxs[r];
        sD[lr] = Ds[r];
      }
    }
  }

  // ================= scan role (all waves): keep per-lane top-3 keys per row =================
  uint32_t tk0[10], tk1[10], tk2[10];
#pragma unroll
  for (int ri = 0; ri < 10; ++ri) {
    if (ri < scnt) {
      const int n = B + sstart + ri;
      const uint32_t c0 = (uint32_t)n * (uint32_t)MCOL + (uint32_t)lane;
      uint32_t t0 = 0u, t1 = 0u, t2 = 0u;
#pragma unroll 8
      for (uint32_t jj = 0; jj < 32; ++jj) {
        uint32_t b = tf_hash(c0 + 64u * jj);
        uint32_t key = (b & 0xFFFFFE00u) | jj;  // u-bits | jj  (m = lane | jj<<6)
        t2 = max(t2, min(min(t0, t1), key));
        t1 = max(t1, min(t0, key));
        t0 = max(t0, key);
      }
      tk0[ri] = t0; tk1[ri] = t1; tk2[ri] = t2;
    }
  }

  __syncthreads();  // stats ready in LDS

  // ================= adjudicate + scatter =================
#pragma unroll
  for (int ri = 0; ri < 10; ++ri) {
    if (ri < scnt) {
      const int n = B + sstart + ri;
      const int lr = sstart + ri;

      uint32_t t0 = tk0[ri], t1 = tk1[ri], t2 = tk2[ri];
      uint32_t kmax = t0;
#pragma unroll
      for (int s = 1; s < 64; s <<= 1)
        kmax = max(kmax, (uint32_t)__shfl_xor((int)kmax, s));

      const float mx = smx[lr], Dp = sD[lr];
      const float pmax = __expf(mx) / Dp;
      const float gstar = gumbel_of_key(kmax);
      const float thr = gstar - (pmax * 1.05f + 2e-4f);

      const float2 xa = ((const float2*)(x1 + (size_t)n * KDIM))[lane];
      const float2 xb = ((const float2*)(kin + (size_t)n * KDIM))[lane];
      const float xk0 = xa.x + xb.x, xk1 = xa.y + xb.y;

      float bestSc = -INFINITY;
      int bestM = 0x7FFFFFFF;

      if (pmax > 0.2f) {
        // -------- exact full-rescan fallback (prob ~0, correctness valve) --------
        xksh[wv][lane * 2] = xk0;
        xksh[wv][lane * 2 + 1] = xk1;
        __builtin_amdgcn_s_waitcnt(0);
        for (uint32_t jj = 0; jj < 32; ++jj) {
          uint32_t m = (uint32_t)lane | (jj << 6);
          uint32_t b = tf_hash((uint32_t)n * (uint32_t)MCOL + m);
          float g = -logf(-logf(bits_to_u(b)));
          float l = 0.f;
          for (int e = 0; e < KDIM; ++e) l += xksh[wv][e] * cw_s[(size_t)m * KDIM + e];
          float p = __expf(l + cb_s[m]) / Dp;
          float sc = p + g;
          if (sc > bestSc || (sc == bestSc && (int)m < bestM)) { bestSc = sc; bestM = (int)m; }
        }
#pragma unroll
        for (int s = 1; s < 64; s <<= 1) {
          float os = __shfl_xor(bestSc, s);
          int om = __shfl_xor(bestM, s);
          if (os > bestSc || (os == bestSc && om < bestM)) { bestSc = os; bestM = om; }
        }
      } else {
        // -------- normal path: adjudicate in-register top-3 candidates --------
#pragma unroll
        for (int s = 0; s < 3; ++s) {
          uint32_t tkv = (s == 0) ? t0 : ((s == 1) ? t1 : t2);
          float g = gumbel_of_key(tkv);
          unsigned long long bl = __ballot(g >= thr);
          while (bl) {
            int src = __ffsll(bl) - 1;
            bl &= bl - 1ull;
            uint32_t kk = (uint32_t)__shfl((int)tkv, src);
            float gc = __shfl(g, src);
            int m = src | (int)((kk & 31u) << 6);
            const float2 cv = ((const float2*)(cw_s + (size_t)m * KDIM))[lane];
            float part = xk0 * cv.x + xk1 * cv.y;
#pragma unroll
            for (int sh = 1; sh < 64; sh <<= 1) part += __shfl_xor(part, sh);
            float p = __expf(part + cb_s[m]) / Dp;
            float sc = p + gc;
            if (sc > bestSc || (sc == bestSc && m < bestM)) { bestSc = sc; bestM = m; }
          }
        }
      }

      float* dst = accum + (size_t)bestM * KDIM + lane * 2;
      atomicAdd(dst + 0, xa.x);
      atomicAdd(dst + 1, xa.y);
    }
  }
}

// ---------------- final: out = accum @ Wd.T + bd ----------------
__global__ void k_final(const float* __restrict__ acc, const float* __restrict__ Wd,
                        const float* __restrict__ bd, float* __restrict__ out) {
  int m = blockIdx.x, j = threadIdx.x;  // 128 threads
  __shared__ float ar[KDIM];
  if (j < 32) ((float4*)ar)[j] = ((const float4*)(acc + (size_t)m * KDIM))[j];
  __syncthreads();
  const float4* wr = (const float4*)(Wd + (size_t)j * KDIM);
  float s = 0.f;
#pragma unroll
  for (int e4 = 0; e4 < 32; ++e4) {
    float4 wv = wr[e4];
    s += wv.x * ar[4 * e4 + 0] + wv.y * ar[4 * e4 + 1]
       + wv.z * ar[4 * e4 + 2] + wv.w * ar[4 * e4 + 3];
  }
  out[(size_t)m * KDIM + j] = s + bd[j];
}

extern "C" void kernel_launch(void* const* d_in, const int* in_sizes, int n_in,
                              void* d_out, int out_size, void* d_ws, size_t ws_size,
                              hipStream_t stream) {
  const float* x1 = (const float*)d_in[0];
  const float* k  = (const float*)d_in[1];
  const float* c  = (const float*)d_in[2];
  const float* Wq = (const float*)d_in[3];
  const float* bq = (const float*)d_in[4];
  const float* Wd = (const float*)d_in[5];
  const float* bd = (const float*)d_in[6];
  float* out = (float*)d_out;

  char* ws = (char*)d_ws;
  size_t off = 0;
  float* cw_s = (float*)(ws + off); off += (size_t)MCOL * KDIM * 4;                   // 1MB
  float* cb_s = (float*)(ws + off); off += 8192;                                      // 8KB
  unsigned short* cwB = (unsigned short*)(ws + off); off += (size_t)MCOL * KDIM * 2;  // 512KB
  float* Wsum = (float*)(ws + off); off += KDIM * KDIM * 4;                           // 64KB
  float* bsum = (float*)(ws + off); off += 4096;
  float* accum = (float*)(ws + off); off += (size_t)MCOL * KDIM * 4;                  // 1MB

  hipMemsetAsync(accum, 0, (size_t)MCOL * KDIM * sizeof(float), stream);
  k_wsum<<<64, 256, 0, stream>>>(Wq, bq, Wsum, bsum);
  k_cw<<<MCOL, 128, 0, stream>>>(c, Wsum, bsum, cw_s, cwB, cb_s);
  k_mega<<<1024, 256, 0, stream>>>(x1, k, (const uint4*)cwB, cb_s, cw_s, accum);
  k_final<<<MCOL, 128, 0, stream>>>(accum, Wd, bd, out);
}